// Round 1
// baseline (876.344 us; speedup 1.0000x reference)
//
#include <hip/hip_runtime.h>
#include <cstdint>
#include <cstddef>

// Problem constants (fixed by the reference file)
#define B_TOT 32768
#define NPART 8
#define NCLUS 512
#define DCL   64
#define DTOT  512
#define BTILE 16
#define CT    128   // centroid c-tile

// ---------------------------------------------------------------------------
// Threefry-2x32 (exactly jax/_src/prng.py threefry2x32 lowering).
// RNG scheme assumption: jax_threefry_partitionable=True (modern JAX default):
//   split  -> foldlike: key_j = cipher(key, (0, j)), both output words
//   bits32 -> per flat index n: bits1 ^ bits2 of cipher(key, (hi(n), lo(n)))
// Fallback (if score-only large error next round): original scheme
//   (iota split-halves pairing (i, i+n/2); bits = x0' / x1').
// ---------------------------------------------------------------------------
__host__ __device__ __forceinline__ void tf2x32(uint32_t k0, uint32_t k1,
    uint32_t x0, uint32_t x1, uint32_t& o0, uint32_t& o1)
{
  const uint32_t k2 = k0 ^ k1 ^ 0x1BD11BDAu;
#define TFR(r) { x0 += x1; x1 = (x1 << r) | (x1 >> (32 - r)); x1 ^= x0; }
  x0 += k0; x1 += k1;
  TFR(13) TFR(15) TFR(26) TFR(6)
  x0 += k1; x1 += k2 + 1u;
  TFR(17) TFR(29) TFR(16) TFR(24)
  x0 += k2; x1 += k0 + 2u;
  TFR(13) TFR(15) TFR(26) TFR(6)
  x0 += k0; x1 += k1 + 3u;
  TFR(17) TFR(29) TFR(16) TFR(24)
  x0 += k1; x1 += k2 + 4u;
  TFR(13) TFR(15) TFR(26) TFR(6)
  x0 += k2; x1 += k0 + 5u;
#undef TFR
  o0 = x0; o1 = x1;
}

__device__ __forceinline__ uint32_t tf_bits32(uint32_t k0, uint32_t k1, uint32_t n)
{
  uint32_t a, b;
  tf2x32(k0, k1, 0u, n, a, b);   // hi word of 64-bit counter is 0 (n < 2^32)
  return a ^ b;                  // partitionable 32-bit path: bits1 ^ bits2
}

// XLA ErfInv32 (Giles polynomial, w = -log1p(-x*x)) — matches xla math.cc
__device__ __forceinline__ float erfinv_xla(float x)
{
  float w = -log1pf(-x * x);
  float p;
  if (w < 5.0f) {
    w = w - 2.5f;
    p = 2.81022636e-08f;
    p = fmaf(p, w, 3.43273939e-07f);
    p = fmaf(p, w, -3.5233877e-06f);
    p = fmaf(p, w, -4.39150654e-06f);
    p = fmaf(p, w, 0.00021858087f);
    p = fmaf(p, w, -0.00125372503f);
    p = fmaf(p, w, -0.00417768164f);
    p = fmaf(p, w, 0.246640727f);
    p = fmaf(p, w, 1.50140941f);
  } else {
    w = __fsqrt_rn(w) - 3.0f;
    p = -0.000200214257f;
    p = fmaf(p, w, 0.000100950558f);
    p = fmaf(p, w, 0.00134934322f);
    p = fmaf(p, w, -0.00367342844f);
    p = fmaf(p, w, 0.00573950773f);
    p = fmaf(p, w, -0.0076224613f);
    p = fmaf(p, w, 0.00943887047f);
    p = fmaf(p, w, 1.00167406f);
    p = fmaf(p, w, 2.83297682f);
  }
  return p * x;
}

// ---------------------------------------------------------------------------
// Main kernel: block = (one partition p) x (16 users). Computes neg_dist for
// all 512 clusters (staged centroid tiles in LDS, transposed), softmax logits
// (written to out), gumbel argmax selection (written to ws sel).
// Thread map: cg = tid&31 -> 4 clusters (cg*4..+3 per tile), bg = tid>>5 -> 2
// users (bg*2, bg*2+1). Row state lives fully in the 32-lane group.
// ---------------------------------------------------------------------------
__global__ __launch_bounds__(256) void qvae_main_kernel(
    const float* __restrict__ user_emb, const float* __restrict__ centroids,
    const int* __restrict__ user_id, float* __restrict__ out_logits,
    int* __restrict__ sel, uint32_t kg0, uint32_t kg1)
{
  __shared__ float cenT[DCL][CT + 8];   // transposed tile, stride 136 (16B-aligned rows)
  __shared__ float uT[DCL][17];         // transposed user slice, padded
  __shared__ float u2s[BTILE];
  __shared__ float c2s[CT];

  const int p = blockIdx.y;
  const int bbase = blockIdx.x * BTILE;
  const int tid = threadIdx.x;

  // stage user slice (16 users x 64 dims of partition p), transposed
  {
    const int b_l = tid >> 4, f = tid & 15;
    const int uid = user_id[bbase + b_l];
    const float4 v = *(const float4*)(user_emb + (size_t)uid * DTOT + p * DCL + f * 4);
    uT[f * 4 + 0][b_l] = v.x;
    uT[f * 4 + 1][b_l] = v.y;
    uT[f * 4 + 2][b_l] = v.z;
    uT[f * 4 + 3][b_l] = v.w;
  }
  __syncthreads();
  if (tid < BTILE) {
    float s = 0.f;
    for (int d = 0; d < DCL; ++d) {
      const float x = uT[d][tid];
      s = __fadd_rn(s, __fmul_rn(x, x));   // mul-then-add like XLA sum(u*u)
    }
    u2s[tid] = s;
  }

  const int cg = tid & 31;
  const int bg = tid >> 5;
  const int b0 = bg * 2;
  const int c0l = cg * 4;

  float ndreg[32];                       // [tile][2b][4c], static-indexed (unrolled)
  float smax[2] = { -3.4e38f, -3.4e38f };
  int   sarg[2] = { 0, 0 };
  float ndmax[2] = { -3.4e38f, -3.4e38f };

#pragma unroll
  for (int t = 0; t < 4; ++t) {
    __syncthreads();   // u2s ready (t=0) / prior-tile epilogue reads done
    // stage centroid tile [64][128] transposed; consecutive lanes -> consecutive c
#pragma unroll
    for (int i = 0; i < 8; ++i) {
      const int q = tid + i * 256;
      const int cr = q & 127;
      const int fb = q >> 7;
      const float4 v = *(const float4*)(centroids +
          ((size_t)p * NCLUS + (size_t)(t * CT + cr)) * DCL + fb * 4);
      cenT[fb * 4 + 0][cr] = v.x;
      cenT[fb * 4 + 1][cr] = v.y;
      cenT[fb * 4 + 2][cr] = v.z;
      cenT[fb * 4 + 3][cr] = v.w;
    }
    __syncthreads();
    if (tid < CT) {    // c2 for this tile (deterministic sequential order)
      float ss = 0.f;
      for (int d = 0; d < DCL; ++d) {
        const float x = cenT[d][tid];
        ss = __fadd_rn(ss, __fmul_rn(x, x));
      }
      c2s[tid] = ss;
    }
    __syncthreads();

    // cross = u . c  (2 users x 4 clusters per thread)
    float ax[2][4] = { {0.f, 0.f, 0.f, 0.f}, {0.f, 0.f, 0.f, 0.f} };
#pragma unroll 4
    for (int d = 0; d < DCL; ++d) {
      const float4 cv = *(const float4*)&cenT[d][c0l];
      const float ua = uT[d][b0];
      const float ub = uT[d][b0 + 1];
      ax[0][0] = fmaf(ua, cv.x, ax[0][0]);
      ax[0][1] = fmaf(ua, cv.y, ax[0][1]);
      ax[0][2] = fmaf(ua, cv.z, ax[0][2]);
      ax[0][3] = fmaf(ua, cv.w, ax[0][3]);
      ax[1][0] = fmaf(ub, cv.x, ax[1][0]);
      ax[1][1] = fmaf(ub, cv.y, ax[1][1]);
      ax[1][2] = fmaf(ub, cv.z, ax[1][2]);
      ax[1][3] = fmaf(ub, cv.w, ax[1][3]);
    }

    // epilogue: neg_dist, gumbel, online argmax/max
    const float4 c2v = *(const float4*)&c2s[c0l];
#pragma unroll
    for (int bi = 0; bi < 2; ++bi) {
      const float u2 = u2s[b0 + bi];
      const int bglob = bbase + b0 + bi;
      const uint32_t nbase =
          ((uint32_t)bglob * 8u + (uint32_t)p) * 512u + (uint32_t)(t * CT + c0l);
#pragma unroll
      for (int ci = 0; ci < 4; ++ci) {
        const float cross = ax[bi][ci];
        const float c2e = (ci == 0) ? c2v.x : (ci == 1) ? c2v.y : (ci == 2) ? c2v.z : c2v.w;
        const float t1 = __fadd_rn(u2, c2e);
        const float dist2 = fmaxf(__fsub_rn(t1, __fmul_rn(2.0f, cross)), 0.0f);
        const float nd = -__fsqrt_rn(__fadd_rn(dist2, 1e-12f));
        ndreg[t * 8 + bi * 4 + ci] = nd;
        // gumbel: gu = max(1e-10, u01*1.0 + 1e-10); g = -log(-log(gu))
        const uint32_t bits = tf_bits32(kg0, kg1, nbase + (uint32_t)ci);
        const float u01 = __uint_as_float((bits >> 9) | 0x3f800000u) - 1.0f;
        const float gu = fmaxf(1e-10f, __fadd_rn(u01, 1e-10f));
        const float g = -logf(-logf(gu));
        const float s = __fadd_rn(nd, g);    // tau = 1.0 -> exact identity
        if (s > smax[bi]) { smax[bi] = s; sarg[bi] = t * CT + c0l + ci; }
        ndmax[bi] = fmaxf(ndmax[bi], nd);
      }
    }
  }

  // butterfly reduce across the 32-lane cluster group (first-index tie-break)
#pragma unroll
  for (int m = 1; m < 32; m <<= 1) {
#pragma unroll
    for (int bi = 0; bi < 2; ++bi) {
      const float os = __shfl_xor(smax[bi], m);
      const int   oa = __shfl_xor(sarg[bi], m);
      if (os > smax[bi] || (os == smax[bi] && oa < sarg[bi])) {
        smax[bi] = os; sarg[bi] = oa;
      }
      ndmax[bi] = fmaxf(ndmax[bi], __shfl_xor(ndmax[bi], m));
    }
  }

  // softmax: exp(nd - rowmax), row sum, divide (matches jax.nn.softmax)
  float Zs[2] = { 0.f, 0.f };
#pragma unroll
  for (int t = 0; t < 4; ++t)
#pragma unroll
    for (int bi = 0; bi < 2; ++bi)
#pragma unroll
      for (int ci = 0; ci < 4; ++ci) {
        const int ix = t * 8 + bi * 4 + ci;
        const float e = expf(__fsub_rn(ndreg[ix], ndmax[bi]));
        ndreg[ix] = e;
        Zs[bi] = __fadd_rn(Zs[bi], e);
      }
#pragma unroll
  for (int m = 1; m < 32; m <<= 1) {
    Zs[0] += __shfl_xor(Zs[0], m);
    Zs[1] += __shfl_xor(Zs[1], m);
  }

#pragma unroll
  for (int bi = 0; bi < 2; ++bi) {
    const int bglob = bbase + b0 + bi;
    float* rowp = out_logits + ((size_t)bglob * 8 + (size_t)p) * 512;
#pragma unroll
    for (int t = 0; t < 4; ++t) {
      float4 o;
      o.x = ndreg[t * 8 + bi * 4 + 0] / Zs[bi];
      o.y = ndreg[t * 8 + bi * 4 + 1] / Zs[bi];
      o.z = ndreg[t * 8 + bi * 4 + 2] / Zs[bi];
      o.w = ndreg[t * 8 + bi * 4 + 3] / Zs[bi];
      *(float4*)(rowp + t * CT + c0l) = o;
    }
  }
  if (cg == 0) {
    sel[(bbase + b0 + 0) * NPART + p] = sarg[0];
    sel[(bbase + b0 + 1) * NPART + p] = sarg[1];
  }
}

// ---------------------------------------------------------------------------
// Score kernel: one 64-lane wave per b. item = eps*std + mu with
// eps = sqrt(2)*erfinv(uniform(ke, (B,512), lo=nextafter(-1,0), hi=1)),
// user_vec = selected centroid per partition. Butterfly dot reduce.
// ---------------------------------------------------------------------------
__global__ __launch_bounds__(256) void qvae_score_kernel(
    const float* __restrict__ centroids, const float* __restrict__ item_mu,
    const float* __restrict__ item_logvar, const int* __restrict__ item_id,
    const int* __restrict__ sel, float* __restrict__ out_score,
    uint32_t ke0, uint32_t ke1)
{
  const int lane = threadIdx.x & 63;
  const int b = blockIdx.x * 4 + (threadIdx.x >> 6);
  const int iid = item_id[b];
  const int pp = lane >> 3;
  const int sc = sel[b * NPART + pp];

  const float* cen = centroids + ((size_t)pp * NCLUS + sc) * DCL + (lane & 7) * 8;
  const float* mu = item_mu + (size_t)iid * DTOT + lane * 8;
  const float* lv = item_logvar + (size_t)iid * DTOT + lane * 8;

  const float4 m0 = *(const float4*)mu;
  const float4 m1 = *(const float4*)(mu + 4);
  const float4 l0 = *(const float4*)lv;
  const float4 l1 = *(const float4*)(lv + 4);
  const float4 q0 = *(const float4*)cen;
  const float4 q1 = *(const float4*)(cen + 4);
  const float mua[8] = { m0.x, m0.y, m0.z, m0.w, m1.x, m1.y, m1.z, m1.w };
  const float lva[8] = { l0.x, l0.y, l0.z, l0.w, l1.x, l1.y, l1.z, l1.w };
  const float cna[8] = { q0.x, q0.y, q0.z, q0.w, q1.x, q1.y, q1.z, q1.w };

  const float LO = __int_as_float(0xBF7FFFFFu);   // nextafter(-1,0)
  const float SQ2 = __int_as_float(0x3FB504F3u);  // float(sqrt(2))
  const uint32_t nb = (uint32_t)b * 512u + (uint32_t)lane * 8u;

  float acc = 0.f;
#pragma unroll
  for (int k = 0; k < 8; ++k) {
    const uint32_t bits = tf_bits32(ke0, ke1, nb + (uint32_t)k);
    const float u01 = __uint_as_float((bits >> 9) | 0x3f800000u) - 1.0f;
    // span (1.0 - nextafter(-1,0)) rounds to exactly 2.0f in f32
    const float uu = fmaxf(LO, __fadd_rn(__fmul_rn(u01, 2.0f), LO));
    const float eps = __fmul_rn(SQ2, erfinv_xla(uu));
    const float sd = expf(__fmul_rn(0.5f, lva[k]));
    const float it = __fadd_rn(__fmul_rn(eps, sd), mua[k]);
    acc = fmaf(cna[k], it, acc);
  }
#pragma unroll
  for (int m = 1; m < 64; m <<= 1) acc += __shfl_xor(acc, m);
  if (lane == 0) out_score[b] = acc;
}

// ---------------------------------------------------------------------------
extern "C" void kernel_launch(void* const* d_in, const int* in_sizes, int n_in,
                              void* d_out, int out_size, void* d_ws, size_t ws_size,
                              hipStream_t stream)
{
  (void)in_sizes; (void)n_in; (void)out_size; (void)ws_size;

  const float* user_emb    = (const float*)d_in[0];
  const float* centroids   = (const float*)d_in[1];
  const float* item_mu     = (const float*)d_in[2];
  const float* item_logvar = (const float*)d_in[3];
  const int*   user_id     = (const int*)d_in[4];
  const int*   item_id     = (const int*)d_in[5];

  float* out_score  = (float*)d_out;            // [B]
  float* out_logits = (float*)d_out + B_TOT;    // [B,P,C]
  int*   sel        = (int*)d_ws;               // [B,P] selected cluster ids

  // host-side key derivation: key(42) = (0,42); foldlike split
  uint32_t kg0, kg1, ke0, ke1;
  tf2x32(0u, 42u, 0u, 0u, kg0, kg1);   // kg = split(key)[0]
  tf2x32(0u, 42u, 0u, 1u, ke0, ke1);   // ke = split(key)[1]

  dim3 g1(B_TOT / BTILE, NPART);
  qvae_main_kernel<<<g1, 256, 0, stream>>>(user_emb, centroids, user_id,
                                           out_logits, sel, kg0, kg1);
  qvae_score_kernel<<<B_TOT / 4, 256, 0, stream>>>(centroids, item_mu, item_logvar,
                                                   item_id, sel, out_score, ke0, ke1);
}

// Round 2
// 758.053 us; speedup vs baseline: 1.1560x; 1.1560x over previous
//
#include <hip/hip_runtime.h>
#include <cstdint>
#include <cstddef>

// Problem constants (fixed by the reference file)
#define B_TOT 32768
#define NPART 8
#define NCLUS 512
#define DCL   64
#define DTOT  512
#define BTILE 16
#define CT    128   // centroid c-tile

// ---------------------------------------------------------------------------
// Threefry-2x32 (exactly jax/_src/prng.py), partitionable scheme (verified R1):
//   split  -> foldlike: key_j = cipher(key, (0, j))
//   bits32 -> per flat index n: bits1 ^ bits2 of cipher(key, (0, n))
// ---------------------------------------------------------------------------
__host__ __device__ __forceinline__ void tf2x32(uint32_t k0, uint32_t k1,
    uint32_t x0, uint32_t x1, uint32_t& o0, uint32_t& o1)
{
  const uint32_t k2 = k0 ^ k1 ^ 0x1BD11BDAu;
#define TFR(r) { x0 += x1; x1 = (x1 << r) | (x1 >> (32 - r)); x1 ^= x0; }
  x0 += k0; x1 += k1;
  TFR(13) TFR(15) TFR(26) TFR(6)
  x0 += k1; x1 += k2 + 1u;
  TFR(17) TFR(29) TFR(16) TFR(24)
  x0 += k2; x1 += k0 + 2u;
  TFR(13) TFR(15) TFR(26) TFR(6)
  x0 += k0; x1 += k1 + 3u;
  TFR(17) TFR(29) TFR(16) TFR(24)
  x0 += k1; x1 += k2 + 4u;
  TFR(13) TFR(15) TFR(26) TFR(6)
  x0 += k2; x1 += k0 + 5u;
#undef TFR
  o0 = x0; o1 = x1;
}

__device__ __forceinline__ uint32_t tf_bits32(uint32_t k0, uint32_t k1, uint32_t n)
{
  uint32_t a, b;
  tf2x32(k0, k1, 0u, n, a, b);
  return a ^ b;
}

// XLA ErfInv32 (Giles polynomial) — matches xla math.cc. Raw sqrt is fine
// (1e-7 rel error on eps, score threshold is 2.66).
__device__ __forceinline__ float erfinv_xla(float x)
{
  float w = -log1pf(-x * x);
  float p;
  if (w < 5.0f) {
    w = w - 2.5f;
    p = 2.81022636e-08f;
    p = fmaf(p, w, 3.43273939e-07f);
    p = fmaf(p, w, -3.5233877e-06f);
    p = fmaf(p, w, -4.39150654e-06f);
    p = fmaf(p, w, 0.00021858087f);
    p = fmaf(p, w, -0.00125372503f);
    p = fmaf(p, w, -0.00417768164f);
    p = fmaf(p, w, 0.246640727f);
    p = fmaf(p, w, 1.50140941f);
  } else {
    w = __builtin_amdgcn_sqrtf(w) - 3.0f;
    p = -0.000200214257f;
    p = fmaf(p, w, 0.000100950558f);
    p = fmaf(p, w, 0.00134934322f);
    p = fmaf(p, w, -0.00367342844f);
    p = fmaf(p, w, 0.00573950773f);
    p = fmaf(p, w, -0.0076224613f);
    p = fmaf(p, w, 0.00943887047f);
    p = fmaf(p, w, 1.00167406f);
    p = fmaf(p, w, 2.83297682f);
  }
  return p * x;
}

// ---------------------------------------------------------------------------
// c2 precompute: c2g[p*512+c] = sum_d centroids[p][c][d]^2  (4096 rows).
// Order-of-summation differences vs numpy are ~1e-6 rel — irrelevant.
// ---------------------------------------------------------------------------
__global__ __launch_bounds__(256) void qvae_c2_kernel(
    const float* __restrict__ centroids, float* __restrict__ c2g)
{
  const int idx = blockIdx.x * 256 + threadIdx.x;   // 0..4095
  const float* row = centroids + (size_t)idx * DCL;
  float s = 0.f;
#pragma unroll
  for (int d = 0; d < DCL; d += 4) {
    const float4 v = *(const float4*)(row + d);
    s = fmaf(v.x, v.x, s);
    s = fmaf(v.y, v.y, s);
    s = fmaf(v.z, v.z, s);
    s = fmaf(v.w, v.w, s);
  }
  c2g[idx] = s;
}

// ---------------------------------------------------------------------------
// Main kernel: block = (one partition p) x (16 users). neg_dist for all 512
// clusters (LDS-staged transposed centroid tiles), softmax logits -> out,
// gumbel argmax -> sel. Thread map: cg=tid&31 -> 4 clusters, bg=tid>>5 -> 2
// users. All transcendentals native (argmax/logits tolerate ~1e-6).
// ---------------------------------------------------------------------------
__global__ __launch_bounds__(256) void qvae_main_kernel(
    const float* __restrict__ user_emb, const float* __restrict__ centroids,
    const float* __restrict__ c2g, const int* __restrict__ user_id,
    float* __restrict__ out_logits, int* __restrict__ sel,
    uint32_t kg0, uint32_t kg1)
{
  __shared__ float cenT[DCL][CT + 8];   // transposed tile, stride 136
  __shared__ float uT[DCL][18];         // transposed users, stride 18 (8B-aligned rows)
  __shared__ float u2s[BTILE];

  const int p = blockIdx.y;
  const int bbase = blockIdx.x * BTILE;
  const int tid = threadIdx.x;

  // stage user slice (16 users x 64 dims of partition p), transposed
  {
    const int b_l = tid >> 4, f = tid & 15;
    const int uid = user_id[bbase + b_l];
    const float4 v = *(const float4*)(user_emb + (size_t)uid * DTOT + p * DCL + f * 4);
    uT[f * 4 + 0][b_l] = v.x;
    uT[f * 4 + 1][b_l] = v.y;
    uT[f * 4 + 2][b_l] = v.z;
    uT[f * 4 + 3][b_l] = v.w;
  }
  __syncthreads();
  // parallel u2: 16 threads/user, 4 dims each, shuffle-reduce over 16 lanes
  {
    const int uu = tid >> 4;
    const int d0 = (tid & 15) * 4;
    float s = 0.f;
#pragma unroll
    for (int j = 0; j < 4; ++j) {
      const float x = uT[d0 + j][uu];
      s = fmaf(x, x, s);
    }
#pragma unroll
    for (int m = 1; m < 16; m <<= 1) s += __shfl_xor(s, m);
    if ((tid & 15) == 0) u2s[uu] = s;
  }

  const int cg = tid & 31;
  const int bg = tid >> 5;
  const int b0 = bg * 2;
  const int c0l = cg * 4;

  float ndreg[32];                       // [tile][2b][4c], static-indexed
  float smax[2] = { -3.4e38f, -3.4e38f };
  int   sarg[2] = { 0, 0 };
  float ndmax[2] = { -3.4e38f, -3.4e38f };

#pragma unroll
  for (int t = 0; t < 4; ++t) {
    __syncthreads();   // uT/u2s ready (t=0) / prior-tile cenT reads done
#pragma unroll
    for (int i = 0; i < 8; ++i) {
      const int q = tid + i * 256;
      const int cr = q & 127;
      const int fb = q >> 7;
      const float4 v = *(const float4*)(centroids +
          ((size_t)p * NCLUS + (size_t)(t * CT + cr)) * DCL + fb * 4);
      cenT[fb * 4 + 0][cr] = v.x;
      cenT[fb * 4 + 1][cr] = v.y;
      cenT[fb * 4 + 2][cr] = v.z;
      cenT[fb * 4 + 3][cr] = v.w;
    }
    __syncthreads();

    // cross = u . c  (2 users x 4 clusters per thread)
    float ax[2][4] = { {0.f, 0.f, 0.f, 0.f}, {0.f, 0.f, 0.f, 0.f} };
#pragma unroll 4
    for (int d = 0; d < DCL; ++d) {
      const float4 cv = *(const float4*)&cenT[d][c0l];
      const float2 uv = *(const float2*)&uT[d][b0];
      ax[0][0] = fmaf(uv.x, cv.x, ax[0][0]);
      ax[0][1] = fmaf(uv.x, cv.y, ax[0][1]);
      ax[0][2] = fmaf(uv.x, cv.z, ax[0][2]);
      ax[0][3] = fmaf(uv.x, cv.w, ax[0][3]);
      ax[1][0] = fmaf(uv.y, cv.x, ax[1][0]);
      ax[1][1] = fmaf(uv.y, cv.y, ax[1][1]);
      ax[1][2] = fmaf(uv.y, cv.z, ax[1][2]);
      ax[1][3] = fmaf(uv.y, cv.w, ax[1][3]);
    }

    // epilogue: neg_dist, gumbel, online argmax/max
    const float4 c2v = *(const float4*)(c2g + (p * NCLUS + t * CT + c0l));
#pragma unroll
    for (int bi = 0; bi < 2; ++bi) {
      const float u2 = u2s[b0 + bi];
      const int bglob = bbase + b0 + bi;
      const uint32_t nbase =
          ((uint32_t)bglob * 8u + (uint32_t)p) * 512u + (uint32_t)(t * CT + c0l);
#pragma unroll
      for (int ci = 0; ci < 4; ++ci) {
        const float cross = ax[bi][ci];
        const float c2e = (ci == 0) ? c2v.x : (ci == 1) ? c2v.y : (ci == 2) ? c2v.z : c2v.w;
        const float t1 = __fadd_rn(u2, c2e);
        const float dist2 = fmaxf(__fsub_rn(t1, __fmul_rn(2.0f, cross)), 0.0f);
        const float nd = -__builtin_amdgcn_sqrtf(__fadd_rn(dist2, 1e-12f));
        ndreg[t * 8 + bi * 4 + ci] = nd;
        // gumbel (feeds argmax only -> native logs fine)
        const uint32_t bits = tf_bits32(kg0, kg1, nbase + (uint32_t)ci);
        const float u01 = __uint_as_float((bits >> 9) | 0x3f800000u) - 1.0f;
        const float gu = fmaxf(1e-10f, __fadd_rn(u01, 1e-10f));
        const float g = -__logf(-__logf(gu));
        const float s = __fadd_rn(nd, g);    // tau = 1.0 -> identity
        if (s > smax[bi]) { smax[bi] = s; sarg[bi] = t * CT + c0l + ci; }
        ndmax[bi] = fmaxf(ndmax[bi], nd);
      }
    }
  }

  // butterfly reduce across the 32-lane cluster group (first-index tie-break)
#pragma unroll
  for (int m = 1; m < 32; m <<= 1) {
#pragma unroll
    for (int bi = 0; bi < 2; ++bi) {
      const float os = __shfl_xor(smax[bi], m);
      const int   oa = __shfl_xor(sarg[bi], m);
      if (os > smax[bi] || (os == smax[bi] && oa < sarg[bi])) {
        smax[bi] = os; sarg[bi] = oa;
      }
      ndmax[bi] = fmaxf(ndmax[bi], __shfl_xor(ndmax[bi], m));
    }
  }

  // softmax: exp(nd - rowmax), row sum, multiply by reciprocal
  float Zs[2] = { 0.f, 0.f };
#pragma unroll
  for (int t = 0; t < 4; ++t)
#pragma unroll
    for (int bi = 0; bi < 2; ++bi)
#pragma unroll
      for (int ci = 0; ci < 4; ++ci) {
        const int ix = t * 8 + bi * 4 + ci;
        const float e = __expf(__fsub_rn(ndreg[ix], ndmax[bi]));
        ndreg[ix] = e;
        Zs[bi] = __fadd_rn(Zs[bi], e);
      }
#pragma unroll
  for (int m = 1; m < 32; m <<= 1) {
    Zs[0] += __shfl_xor(Zs[0], m);
    Zs[1] += __shfl_xor(Zs[1], m);
  }
  const float inv0 = __builtin_amdgcn_rcpf(Zs[0]);
  const float inv1 = __builtin_amdgcn_rcpf(Zs[1]);

#pragma unroll
  for (int bi = 0; bi < 2; ++bi) {
    const float inv = bi ? inv1 : inv0;
    const int bglob = bbase + b0 + bi;
    float* rowp = out_logits + ((size_t)bglob * 8 + (size_t)p) * 512;
#pragma unroll
    for (int t = 0; t < 4; ++t) {
      float4 o;
      o.x = ndreg[t * 8 + bi * 4 + 0] * inv;
      o.y = ndreg[t * 8 + bi * 4 + 1] * inv;
      o.z = ndreg[t * 8 + bi * 4 + 2] * inv;
      o.w = ndreg[t * 8 + bi * 4 + 3] * inv;
      *(float4*)(rowp + t * CT + c0l) = o;
    }
  }
  if (cg == 0) {
    sel[(bbase + b0 + 0) * NPART + p] = sarg[0];
    sel[(bbase + b0 + 1) * NPART + p] = sarg[1];
  }
}

// ---------------------------------------------------------------------------
// Score kernel: one 64-lane wave per b. item = eps*std + mu with
// eps = sqrt(2)*erfinv(uniform(ke, (B,512), nextafter(-1,0), 1)); dot with
// selected centroids. Butterfly reduce.
// ---------------------------------------------------------------------------
__global__ __launch_bounds__(256) void qvae_score_kernel(
    const float* __restrict__ centroids, const float* __restrict__ item_mu,
    const float* __restrict__ item_logvar, const int* __restrict__ item_id,
    const int* __restrict__ sel, float* __restrict__ out_score,
    uint32_t ke0, uint32_t ke1)
{
  const int lane = threadIdx.x & 63;
  const int b = blockIdx.x * 4 + (threadIdx.x >> 6);
  const int iid = item_id[b];
  const int pp = lane >> 3;
  const int sc = sel[b * NPART + pp];

  const float* cen = centroids + ((size_t)pp * NCLUS + sc) * DCL + (lane & 7) * 8;
  const float* mu = item_mu + (size_t)iid * DTOT + lane * 8;
  const float* lv = item_logvar + (size_t)iid * DTOT + lane * 8;

  const float4 m0 = *(const float4*)mu;
  const float4 m1 = *(const float4*)(mu + 4);
  const float4 l0 = *(const float4*)lv;
  const float4 l1 = *(const float4*)(lv + 4);
  const float4 q0 = *(const float4*)cen;
  const float4 q1 = *(const float4*)(cen + 4);
  const float mua[8] = { m0.x, m0.y, m0.z, m0.w, m1.x, m1.y, m1.z, m1.w };
  const float lva[8] = { l0.x, l0.y, l0.z, l0.w, l1.x, l1.y, l1.z, l1.w };
  const float cna[8] = { q0.x, q0.y, q0.z, q0.w, q1.x, q1.y, q1.z, q1.w };

  const float LO = __int_as_float(0xBF7FFFFFu);   // nextafter(-1,0)
  const float SQ2 = __int_as_float(0x3FB504F3u);  // float(sqrt(2))
  const uint32_t nb = (uint32_t)b * 512u + (uint32_t)lane * 8u;

  float acc = 0.f;
#pragma unroll
  for (int k = 0; k < 8; ++k) {
    const uint32_t bits = tf_bits32(ke0, ke1, nb + (uint32_t)k);
    const float u01 = __uint_as_float((bits >> 9) | 0x3f800000u) - 1.0f;
    const float uu = fmaxf(LO, __fadd_rn(__fmul_rn(u01, 2.0f), LO));
    const float eps = __fmul_rn(SQ2, erfinv_xla(uu));
    const float sd = __expf(__fmul_rn(0.5f, lva[k]));
    const float it = __fadd_rn(__fmul_rn(eps, sd), mua[k]);
    acc = fmaf(cna[k], it, acc);
  }
#pragma unroll
  for (int m = 1; m < 64; m <<= 1) acc += __shfl_xor(acc, m);
  if (lane == 0) out_score[b] = acc;
}

// ---------------------------------------------------------------------------
extern "C" void kernel_launch(void* const* d_in, const int* in_sizes, int n_in,
                              void* d_out, int out_size, void* d_ws, size_t ws_size,
                              hipStream_t stream)
{
  (void)in_sizes; (void)n_in; (void)out_size; (void)ws_size;

  const float* user_emb    = (const float*)d_in[0];
  const float* centroids   = (const float*)d_in[1];
  const float* item_mu     = (const float*)d_in[2];
  const float* item_logvar = (const float*)d_in[3];
  const int*   user_id     = (const int*)d_in[4];
  const int*   item_id     = (const int*)d_in[5];

  float* out_score  = (float*)d_out;            // [B]
  float* out_logits = (float*)d_out + B_TOT;    // [B,P,C]
  int*   sel        = (int*)d_ws;               // [B,P] selected cluster ids
  float* c2g        = (float*)((char*)d_ws + (size_t)B_TOT * NPART * 4);  // [P,C]

  // host-side key derivation: key(42) = (0,42); foldlike split
  uint32_t kg0, kg1, ke0, ke1;
  tf2x32(0u, 42u, 0u, 0u, kg0, kg1);
  tf2x32(0u, 42u, 0u, 1u, ke0, ke1);

  qvae_c2_kernel<<<NPART * NCLUS / 256, 256, 0, stream>>>(centroids, c2g);

  dim3 g1(B_TOT / BTILE, NPART);
  qvae_main_kernel<<<g1, 256, 0, stream>>>(user_emb, centroids, c2g, user_id,
                                           out_logits, sel, kg0, kg1);
  qvae_score_kernel<<<B_TOT / 4, 256, 0, stream>>>(centroids, item_mu, item_logvar,
                                                   item_id, sel, out_score, ke0, ke1);
}

// Round 3
// 514.395 us; speedup vs baseline: 1.7036x; 1.4737x over previous
//
#include <hip/hip_runtime.h>
#include <cstdint>
#include <cstddef>

// Problem constants (fixed by the reference file)
#define B_TOT 32768
#define NPART 8
#define NCLUS 512
#define DCL   64
#define DTOT  512
#define BTILE 16

typedef _Float16 half8 __attribute__((ext_vector_type(8)));
typedef float    f32x4 __attribute__((ext_vector_type(4)));

// ---------------------------------------------------------------------------
// Threefry-2x32 (exactly jax/_src/prng.py), partitionable scheme (verified R1):
//   split  -> foldlike: key_j = cipher(key, (0, j))
//   bits32 -> per flat index n: bits1 ^ bits2 of cipher(key, (0, n))
// ---------------------------------------------------------------------------
__host__ __device__ __forceinline__ void tf2x32(uint32_t k0, uint32_t k1,
    uint32_t x0, uint32_t x1, uint32_t& o0, uint32_t& o1)
{
  const uint32_t k2 = k0 ^ k1 ^ 0x1BD11BDAu;
#define TFR(r) { x0 += x1; x1 = (x1 << r) | (x1 >> (32 - r)); x1 ^= x0; }
  x0 += k0; x1 += k1;
  TFR(13) TFR(15) TFR(26) TFR(6)
  x0 += k1; x1 += k2 + 1u;
  TFR(17) TFR(29) TFR(16) TFR(24)
  x0 += k2; x1 += k0 + 2u;
  TFR(13) TFR(15) TFR(26) TFR(6)
  x0 += k0; x1 += k1 + 3u;
  TFR(17) TFR(29) TFR(16) TFR(24)
  x0 += k1; x1 += k2 + 4u;
  TFR(13) TFR(15) TFR(26) TFR(6)
  x0 += k2; x1 += k0 + 5u;
#undef TFR
  o0 = x0; o1 = x1;
}

__device__ __forceinline__ uint32_t tf_bits32(uint32_t k0, uint32_t k1, uint32_t n)
{
  uint32_t a, b;
  tf2x32(k0, k1, 0u, n, a, b);
  return a ^ b;
}

// XLA ErfInv32 (Giles polynomial) — matches xla math.cc
__device__ __forceinline__ float erfinv_xla(float x)
{
  float w = -log1pf(-x * x);
  float p;
  if (w < 5.0f) {
    w = w - 2.5f;
    p = 2.81022636e-08f;
    p = fmaf(p, w, 3.43273939e-07f);
    p = fmaf(p, w, -3.5233877e-06f);
    p = fmaf(p, w, -4.39150654e-06f);
    p = fmaf(p, w, 0.00021858087f);
    p = fmaf(p, w, -0.00125372503f);
    p = fmaf(p, w, -0.00417768164f);
    p = fmaf(p, w, 0.246640727f);
    p = fmaf(p, w, 1.50140941f);
  } else {
    w = __builtin_amdgcn_sqrtf(w) - 3.0f;
    p = -0.000200214257f;
    p = fmaf(p, w, 0.000100950558f);
    p = fmaf(p, w, 0.00134934322f);
    p = fmaf(p, w, -0.00367342844f);
    p = fmaf(p, w, 0.00573950773f);
    p = fmaf(p, w, -0.0076224613f);
    p = fmaf(p, w, 0.00943887047f);
    p = fmaf(p, w, 1.00167406f);
    p = fmaf(p, w, 2.83297682f);
  }
  return p * x;
}

// ---------------------------------------------------------------------------
// Prep: per centroid row (p*512+c): c2 (EXACT same fmaf order as round 2 —
// passed twice) and fp16 hi/lo split image, layout [row][hi 64 | lo 64].
// ---------------------------------------------------------------------------
__global__ __launch_bounds__(256) void qvae_prep_kernel(
    const float* __restrict__ centroids, float* __restrict__ c2g,
    _Float16* __restrict__ cimg)
{
  const int idx = blockIdx.x * 256 + threadIdx.x;   // 0..4095
  const float* row = centroids + (size_t)idx * DCL;
  _Float16* orow = cimg + (size_t)idx * 128;
  float s = 0.f;
#pragma unroll
  for (int d = 0; d < DCL; d += 4) {
    const float4 v = *(const float4*)(row + d);
    s = fmaf(v.x, v.x, s);
    s = fmaf(v.y, v.y, s);
    s = fmaf(v.z, v.z, s);
    s = fmaf(v.w, v.w, s);
  }
  c2g[idx] = s;
#pragma unroll
  for (int d = 0; d < DCL; d += 8) {
    const float4 v0 = *(const float4*)(row + d);
    const float4 v1 = *(const float4*)(row + d + 4);
    const float vv[8] = { v0.x, v0.y, v0.z, v0.w, v1.x, v1.y, v1.z, v1.w };
    half8 hh, ll;
#pragma unroll
    for (int j = 0; j < 8; ++j) {
      const _Float16 h = (_Float16)vv[j];
      hh[j] = h;
      ll[j] = (_Float16)(vv[j] - (float)h);
    }
    *(half8*)(orow + d) = hh;
    *(half8*)(orow + 64 + d) = ll;
  }
}

// ---------------------------------------------------------------------------
// Main kernel: block = 1 partition x 16 users, 4 waves. cross via fp16-split
// MFMA (6x mfma_f32_16x16x32_f16 per 16-cluster tile: uh*ch k0/k1, ul*ch,
// uh*cl — ul*cl ~2^-22 dropped). B-frags read straight from L2-resident fp16
// image (no LDS staging). C/D layout: col=lane&15, row=(lane>>4)*4+reg.
// Softmax without max-subtraction (identical math; nd in [-30,-4], safe).
// ---------------------------------------------------------------------------
__global__ __launch_bounds__(256, 4) void qvae_main_kernel(
    const float* __restrict__ user_emb, const _Float16* __restrict__ cimg,
    const float* __restrict__ c2g, const int* __restrict__ user_id,
    float* __restrict__ out_logits, int* __restrict__ sel,
    uint32_t kg0, uint32_t kg1)
{
  __shared__ float u2s[BTILE];
  __shared__ float zZ[4][BTILE];
  __shared__ float zS[4][BTILE];
  __shared__ int   zA[4][BTILE];

  const int p = blockIdx.y;
  const int bbase = blockIdx.x * BTILE;
  const int tid = threadIdx.x;
  const int w  = tid >> 6;    // wave 0..3
  const int l  = tid & 63;
  const int lr = l & 15;      // A-row / B-col lane index
  const int q  = l >> 4;      // k-quarter

  // ---- A fragments (16 users x 64 dims, fp16 split) + u2 ----
  const int uid = user_id[bbase + lr];
  const float* urow = user_emb + (size_t)uid * DTOT + p * DCL;
  float uf[16];
  {
    const float4 a0 = *(const float4*)(urow + q * 8);
    const float4 a1 = *(const float4*)(urow + q * 8 + 4);
    const float4 a2 = *(const float4*)(urow + 32 + q * 8);
    const float4 a3 = *(const float4*)(urow + 32 + q * 8 + 4);
    uf[0]=a0.x;  uf[1]=a0.y;  uf[2]=a0.z;  uf[3]=a0.w;
    uf[4]=a1.x;  uf[5]=a1.y;  uf[6]=a1.z;  uf[7]=a1.w;
    uf[8]=a2.x;  uf[9]=a2.y;  uf[10]=a2.z; uf[11]=a2.w;
    uf[12]=a3.x; uf[13]=a3.y; uf[14]=a3.z; uf[15]=a3.w;
  }
  half8 ah[2], al[2];
#pragma unroll
  for (int m = 0; m < 2; ++m)
#pragma unroll
    for (int j = 0; j < 8; ++j) {
      const float v = uf[m * 8 + j];
      const _Float16 h = (_Float16)v;
      ah[m][j] = h;
      al[m][j] = (_Float16)(v - (float)h);
    }
  {
    float s = 0.f;
#pragma unroll
    for (int i = 0; i < 16; ++i) s = fmaf(uf[i], uf[i], s);
    s += __shfl_xor(s, 16);
    s += __shfl_xor(s, 32);     // all lanes sharing lr now hold full u2[lr]
    if (tid < BTILE) u2s[tid] = s;
  }
  __syncthreads();
  float u2r[4];
  {
    const float4 uv = *(const float4*)&u2s[q * 4];
    u2r[0]=uv.x; u2r[1]=uv.y; u2r[2]=uv.z; u2r[3]=uv.w;
  }

  // threefry flat-index base for this lane's 4 rows: n = nbase + col + r*4096
  const uint32_t nbase = ((uint32_t)(bbase + q * 4) * 8u + (uint32_t)p) * 512u;

  float ereg[32];
  float Zs[4]  = { 0.f, 0.f, 0.f, 0.f };
  float smx[4] = { -3.4e38f, -3.4e38f, -3.4e38f, -3.4e38f };
  int   sag[4] = { 0, 0, 0, 0 };

#pragma unroll
  for (int t = 0; t < 4; ++t) {
#pragma unroll
    for (int ct = 0; ct < 2; ++ct) {
      const int ctile = t * 8 + w * 2 + ct;          // 0..31
      const int col = ctile * 16 + lr;               // this lane's cluster
      const _Float16* crow = cimg + ((size_t)p * NCLUS + (size_t)col) * 128;
      const half8 bh0 = *(const half8*)(crow + q * 8);
      const half8 bh1 = *(const half8*)(crow + 32 + q * 8);
      const half8 bl0 = *(const half8*)(crow + 64 + q * 8);
      const half8 bl1 = *(const half8*)(crow + 96 + q * 8);
      f32x4 acc = { 0.f, 0.f, 0.f, 0.f };
      acc = __builtin_amdgcn_mfma_f32_16x16x32_f16(ah[0], bh0, acc, 0, 0, 0);
      acc = __builtin_amdgcn_mfma_f32_16x16x32_f16(ah[1], bh1, acc, 0, 0, 0);
      acc = __builtin_amdgcn_mfma_f32_16x16x32_f16(al[0], bh0, acc, 0, 0, 0);
      acc = __builtin_amdgcn_mfma_f32_16x16x32_f16(al[1], bh1, acc, 0, 0, 0);
      acc = __builtin_amdgcn_mfma_f32_16x16x32_f16(ah[0], bl0, acc, 0, 0, 0);
      acc = __builtin_amdgcn_mfma_f32_16x16x32_f16(ah[1], bl1, acc, 0, 0, 0);

      const float c2v = c2g[p * NCLUS + col];
      const uint32_t ncol = nbase + (uint32_t)col;
#pragma unroll
      for (int r = 0; r < 4; ++r) {
        const float u2c2 = __fadd_rn(u2r[r], c2v);
        const float d2 = fmaxf(fmaf(-2.0f, acc[r], u2c2), 0.0f);
        const float qd = __builtin_amdgcn_sqrtf(__fadd_rn(d2, 1e-12f)); // = -nd
        const uint32_t bits = tf_bits32(kg0, kg1, ncol + (uint32_t)r * 4096u);
        const float u01 = __uint_as_float((bits >> 9) | 0x3f800000u) - 1.0f;
        const float gu = fmaxf(1e-10f, __fadd_rn(u01, 1e-10f));
        const float g = -__logf(-__logf(gu));
        const float sc = __fsub_rn(g, qd);           // nd + g
        if (sc > smx[r]) { smx[r] = sc; sag[r] = col; }
        const float e = __expf(-qd);                 // exp(nd), no max-sub
        ereg[(t * 2 + ct) * 4 + r] = e;
        Zs[r] = __fadd_rn(Zs[r], e);
      }
    }
  }

  // reduce across the 16 lanes (same q) holding this row set
#pragma unroll
  for (int m = 1; m < 16; m <<= 1) {
#pragma unroll
    for (int r = 0; r < 4; ++r) {
      Zs[r] += __shfl_xor(Zs[r], m);
      const float os = __shfl_xor(smx[r], m);
      const int   oa = __shfl_xor(sag[r], m);
      if (os > smx[r] || (os == smx[r] && oa < sag[r])) { smx[r] = os; sag[r] = oa; }
    }
  }
  if (lr == 0) {
#pragma unroll
    for (int r = 0; r < 4; ++r) {
      zZ[w][q * 4 + r] = Zs[r];
      zS[w][q * 4 + r] = smx[r];
      zA[w][q * 4 + r] = sag[r];
    }
  }
  __syncthreads();

  // cross-wave combine (4 waves hold different cluster columns of same rows)
  float Zf[4]  = { 0.f, 0.f, 0.f, 0.f };
  float smf[4] = { -3.4e38f, -3.4e38f, -3.4e38f, -3.4e38f };
  int   saf[4] = { 0, 0, 0, 0 };
#pragma unroll
  for (int wv = 0; wv < 4; ++wv) {
    const float4 zz = *(const float4*)&zZ[wv][q * 4];
    const float4 ss = *(const float4*)&zS[wv][q * 4];
    const int4   aa = *(const int4*)&zA[wv][q * 4];
    const float zv[4] = { zz.x, zz.y, zz.z, zz.w };
    const float sv[4] = { ss.x, ss.y, ss.z, ss.w };
    const int   av[4] = { aa.x, aa.y, aa.z, aa.w };
#pragma unroll
    for (int r = 0; r < 4; ++r) {
      Zf[r] = __fadd_rn(Zf[r], zv[r]);
      if (sv[r] > smf[r] || (sv[r] == smf[r] && av[r] < saf[r])) {
        smf[r] = sv[r]; saf[r] = av[r];
      }
    }
  }

  float inv[4];
#pragma unroll
  for (int r = 0; r < 4; ++r) inv[r] = __builtin_amdgcn_rcpf(Zf[r]);

  float* obase = out_logits + ((size_t)(bbase + q * 4) * 8 + p) * 512 + lr;
#pragma unroll
  for (int t = 0; t < 4; ++t)
#pragma unroll
    for (int ct = 0; ct < 2; ++ct) {
      const int cof = (t * 8 + w * 2 + ct) * 16;
#pragma unroll
      for (int r = 0; r < 4; ++r)
        obase[(size_t)r * 4096 + cof] = ereg[(t * 2 + ct) * 4 + r] * inv[r];
    }
  if (w == 0 && lr == 0) {
#pragma unroll
    for (int r = 0; r < 4; ++r)
      sel[(bbase + q * 4 + r) * NPART + p] = saf[r];
  }
}

// ---------------------------------------------------------------------------
// Score kernel (unchanged from round 2): one 64-lane wave per b.
// ---------------------------------------------------------------------------
__global__ __launch_bounds__(256) void qvae_score_kernel(
    const float* __restrict__ centroids, const float* __restrict__ item_mu,
    const float* __restrict__ item_logvar, const int* __restrict__ item_id,
    const int* __restrict__ sel, float* __restrict__ out_score,
    uint32_t ke0, uint32_t ke1)
{
  const int lane = threadIdx.x & 63;
  const int b = blockIdx.x * 4 + (threadIdx.x >> 6);
  const int iid = item_id[b];
  const int pp = lane >> 3;
  const int sc = sel[b * NPART + pp];

  const float* cen = centroids + ((size_t)pp * NCLUS + sc) * DCL + (lane & 7) * 8;
  const float* mu = item_mu + (size_t)iid * DTOT + lane * 8;
  const float* lv = item_logvar + (size_t)iid * DTOT + lane * 8;

  const float4 m0 = *(const float4*)mu;
  const float4 m1 = *(const float4*)(mu + 4);
  const float4 l0 = *(const float4*)lv;
  const float4 l1 = *(const float4*)(lv + 4);
  const float4 q0 = *(const float4*)cen;
  const float4 q1 = *(const float4*)(cen + 4);
  const float mua[8] = { m0.x, m0.y, m0.z, m0.w, m1.x, m1.y, m1.z, m1.w };
  const float lva[8] = { l0.x, l0.y, l0.z, l0.w, l1.x, l1.y, l1.z, l1.w };
  const float cna[8] = { q0.x, q0.y, q0.z, q0.w, q1.x, q1.y, q1.z, q1.w };

  const float LO = __int_as_float(0xBF7FFFFFu);   // nextafter(-1,0)
  const float SQ2 = __int_as_float(0x3FB504F3u);  // float(sqrt(2))
  const uint32_t nb = (uint32_t)b * 512u + (uint32_t)lane * 8u;

  float acc = 0.f;
#pragma unroll
  for (int k = 0; k < 8; ++k) {
    const uint32_t bits = tf_bits32(ke0, ke1, nb + (uint32_t)k);
    const float u01 = __uint_as_float((bits >> 9) | 0x3f800000u) - 1.0f;
    const float uu = fmaxf(LO, __fadd_rn(__fmul_rn(u01, 2.0f), LO));
    const float eps = __fmul_rn(SQ2, erfinv_xla(uu));
    const float sd = __expf(__fmul_rn(0.5f, lva[k]));
    const float it = __fadd_rn(__fmul_rn(eps, sd), mua[k]);
    acc = fmaf(cna[k], it, acc);
  }
#pragma unroll
  for (int m = 1; m < 64; m <<= 1) acc += __shfl_xor(acc, m);
  if (lane == 0) out_score[b] = acc;
}

// ---------------------------------------------------------------------------
extern "C" void kernel_launch(void* const* d_in, const int* in_sizes, int n_in,
                              void* d_out, int out_size, void* d_ws, size_t ws_size,
                              hipStream_t stream)
{
  (void)in_sizes; (void)n_in; (void)out_size; (void)ws_size;

  const float* user_emb    = (const float*)d_in[0];
  const float* centroids   = (const float*)d_in[1];
  const float* item_mu     = (const float*)d_in[2];
  const float* item_logvar = (const float*)d_in[3];
  const int*   user_id     = (const int*)d_in[4];
  const int*   item_id     = (const int*)d_in[5];

  float* out_score  = (float*)d_out;            // [B]
  float* out_logits = (float*)d_out + B_TOT;    // [B,P,C]

  // ws layout: sel [B*P] int (1 MB) | c2g [P*C] f32 (16 KB) | cimg [P*C][128] f16 (1 MB)
  int*       sel  = (int*)d_ws;
  float*     c2g  = (float*)((char*)d_ws + (size_t)B_TOT * NPART * 4);
  _Float16*  cimg = (_Float16*)((char*)d_ws + (size_t)B_TOT * NPART * 4
                                + (size_t)NPART * NCLUS * 4);   // 16B-aligned

  // host-side key derivation: key(42) = (0,42); foldlike split
  uint32_t kg0, kg1, ke0, ke1;
  tf2x32(0u, 42u, 0u, 0u, kg0, kg1);
  tf2x32(0u, 42u, 0u, 1u, ke0, ke1);

  qvae_prep_kernel<<<NPART * NCLUS / 256, 256, 0, stream>>>(centroids, c2g, cimg);

  dim3 g1(B_TOT / BTILE, NPART);
  qvae_main_kernel<<<g1, 256, 0, stream>>>(user_emb, cimg, c2g, user_id,
                                           out_logits, sel, kg0, kg1);
  qvae_score_kernel<<<B_TOT / 4, 256, 0, stream>>>(centroids, item_mu, item_logvar,
                                                   item_id, sel, out_score, ke0, ke1);
}

// Round 4
// 482.946 us; speedup vs baseline: 1.8146x; 1.0651x over previous
//
#include <hip/hip_runtime.h>
#include <cstdint>
#include <cstddef>

// Problem constants (fixed by the reference file)
#define B_TOT 32768
#define NPART 8
#define NCLUS 512
#define DCL   64
#define DTOT  512
#define BTILE 16
#define ROWB  272   // cimg row bytes: 128B hi + 128B lo + 4B c2 + 12B pad (16B-mult)

typedef _Float16 half8 __attribute__((ext_vector_type(8)));
typedef float    f32x4 __attribute__((ext_vector_type(4)));

// ---------------------------------------------------------------------------
// Threefry-2x32 (exactly jax/_src/prng.py), partitionable scheme (verified R1):
//   split  -> foldlike: key_j = cipher(key, (0, j))
//   bits32 -> per flat index n: bits1 ^ bits2 of cipher(key, (0, n))
// ---------------------------------------------------------------------------
__host__ __device__ __forceinline__ void tf2x32(uint32_t k0, uint32_t k1,
    uint32_t x0, uint32_t x1, uint32_t& o0, uint32_t& o1)
{
  const uint32_t k2 = k0 ^ k1 ^ 0x1BD11BDAu;
#define TFR(r) { x0 += x1; x1 = (x1 << r) | (x1 >> (32 - r)); x1 ^= x0; }
  x0 += k0; x1 += k1;
  TFR(13) TFR(15) TFR(26) TFR(6)
  x0 += k1; x1 += k2 + 1u;
  TFR(17) TFR(29) TFR(16) TFR(24)
  x0 += k2; x1 += k0 + 2u;
  TFR(13) TFR(15) TFR(26) TFR(6)
  x0 += k0; x1 += k1 + 3u;
  TFR(17) TFR(29) TFR(16) TFR(24)
  x0 += k1; x1 += k2 + 4u;
  TFR(13) TFR(15) TFR(26) TFR(6)
  x0 += k2; x1 += k0 + 5u;
#undef TFR
  o0 = x0; o1 = x1;
}

__device__ __forceinline__ uint32_t tf_bits32(uint32_t k0, uint32_t k1, uint32_t n)
{
  uint32_t a, b;
  tf2x32(k0, k1, 0u, n, a, b);
  return a ^ b;
}

// XLA ErfInv32 (Giles polynomial) — matches xla math.cc
__device__ __forceinline__ float erfinv_xla(float x)
{
  float w = -log1pf(-x * x);
  float p;
  if (w < 5.0f) {
    w = w - 2.5f;
    p = 2.81022636e-08f;
    p = fmaf(p, w, 3.43273939e-07f);
    p = fmaf(p, w, -3.5233877e-06f);
    p = fmaf(p, w, -4.39150654e-06f);
    p = fmaf(p, w, 0.00021858087f);
    p = fmaf(p, w, -0.00125372503f);
    p = fmaf(p, w, -0.00417768164f);
    p = fmaf(p, w, 0.246640727f);
    p = fmaf(p, w, 1.50140941f);
  } else {
    w = __builtin_amdgcn_sqrtf(w) - 3.0f;
    p = -0.000200214257f;
    p = fmaf(p, w, 0.000100950558f);
    p = fmaf(p, w, 0.00134934322f);
    p = fmaf(p, w, -0.00367342844f);
    p = fmaf(p, w, 0.00573950773f);
    p = fmaf(p, w, -0.0076224613f);
    p = fmaf(p, w, 0.00943887047f);
    p = fmaf(p, w, 1.00167406f);
    p = fmaf(p, w, 2.83297682f);
  }
  return p * x;
}

// ---------------------------------------------------------------------------
// Prep: per centroid row (p*512+c): fp16 hi/lo split + c2 (same fmaf order as
// R2/R3 — passed twice), packed in one 272-byte row: [hi 128B | lo 128B | c2].
// ---------------------------------------------------------------------------
__global__ __launch_bounds__(256) void qvae_prep_kernel(
    const float* __restrict__ centroids, _Float16* __restrict__ cimg)
{
  const int idx = blockIdx.x * 256 + threadIdx.x;   // 0..4095
  const float* row = centroids + (size_t)idx * DCL;
  _Float16* orow = (_Float16*)((char*)cimg + (size_t)idx * ROWB);
  float s = 0.f;
#pragma unroll
  for (int d = 0; d < DCL; d += 4) {
    const float4 v = *(const float4*)(row + d);
    s = fmaf(v.x, v.x, s);
    s = fmaf(v.y, v.y, s);
    s = fmaf(v.z, v.z, s);
    s = fmaf(v.w, v.w, s);
  }
  *(float*)(orow + 128) = s;
#pragma unroll
  for (int d = 0; d < DCL; d += 8) {
    const float4 v0 = *(const float4*)(row + d);
    const float4 v1 = *(const float4*)(row + d + 4);
    const float vv[8] = { v0.x, v0.y, v0.z, v0.w, v1.x, v1.y, v1.z, v1.w };
    half8 hh, ll;
#pragma unroll
    for (int j = 0; j < 8; ++j) {
      const _Float16 h = (_Float16)vv[j];
      hh[j] = h;
      ll[j] = (_Float16)(vv[j] - (float)h);
    }
    *(half8*)(orow + d) = hh;
    *(half8*)(orow + 64 + d) = ll;
  }
}

// ---------------------------------------------------------------------------
// Main kernel: block = 1 partition x 16 users, 4 waves. fp16-split MFMA cross,
// software-pipelined over 8 column-tiles (2-buffer prefetch of B-frags + c2
// from the L2-resident 272B-row image). Gumbel-argmax + softmax fused.
// C/D layout: col=lane&15, row=(lane>>4)*4+reg (verified).
// ---------------------------------------------------------------------------
__global__ __launch_bounds__(256, 4) void qvae_main_kernel(
    const float* __restrict__ user_emb, const _Float16* __restrict__ cimg,
    const int* __restrict__ user_id, float* __restrict__ out_logits,
    int* __restrict__ sel, uint32_t kg0, uint32_t kg1)
{
  __shared__ float u2s[BTILE];
  __shared__ float zZ[4][BTILE];
  __shared__ float zS[4][BTILE];
  __shared__ int   zA[4][BTILE];

  const int p = blockIdx.y;
  const int bbase = blockIdx.x * BTILE;
  const int tid = threadIdx.x;
  const int w  = tid >> 6;    // wave 0..3
  const int l  = tid & 63;
  const int lr = l & 15;      // A-row / B-col lane index
  const int q  = l >> 4;      // k-quarter

  // ---- A fragments (16 users x 64 dims, fp16 split) + u2 ----
  const int uid = user_id[bbase + lr];
  const float* urow = user_emb + (size_t)uid * DTOT + p * DCL;
  float uf[16];
  {
    const float4 a0 = *(const float4*)(urow + q * 8);
    const float4 a1 = *(const float4*)(urow + q * 8 + 4);
    const float4 a2 = *(const float4*)(urow + 32 + q * 8);
    const float4 a3 = *(const float4*)(urow + 32 + q * 8 + 4);
    uf[0]=a0.x;  uf[1]=a0.y;  uf[2]=a0.z;  uf[3]=a0.w;
    uf[4]=a1.x;  uf[5]=a1.y;  uf[6]=a1.z;  uf[7]=a1.w;
    uf[8]=a2.x;  uf[9]=a2.y;  uf[10]=a2.z; uf[11]=a2.w;
    uf[12]=a3.x; uf[13]=a3.y; uf[14]=a3.z; uf[15]=a3.w;
  }
  half8 ah[2], al[2];
#pragma unroll
  for (int m = 0; m < 2; ++m)
#pragma unroll
    for (int j = 0; j < 8; ++j) {
      const float v = uf[m * 8 + j];
      const _Float16 h = (_Float16)v;
      ah[m][j] = h;
      al[m][j] = (_Float16)(v - (float)h);
    }
  {
    float s = 0.f;
#pragma unroll
    for (int i = 0; i < 16; ++i) s = fmaf(uf[i], uf[i], s);
    s += __shfl_xor(s, 16);
    s += __shfl_xor(s, 32);     // all lanes sharing lr now hold full u2[lr]
    if (tid < BTILE) u2s[tid] = s;
  }
  __syncthreads();
  float u2r[4];
  {
    const float4 uv = *(const float4*)&u2s[q * 4];
    u2r[0]=uv.x; u2r[1]=uv.y; u2r[2]=uv.z; u2r[3]=uv.w;
  }

  // per-wave/lane bases: cluster col = wcol + CDELT(i); threefry n = nbw + ...
  const int wcol = w * 32 + lr;
  const uint32_t nbw =
      ((uint32_t)(bbase + q * 4) * 8u + (uint32_t)p) * 512u + (uint32_t)wcol;
  const char* cb = (const char*)cimg;
  const uint32_t rowoff =
      ((uint32_t)p * NCLUS + (uint32_t)wcol) * (uint32_t)ROWB + (uint32_t)q * 16u;

  float ereg[32];
  float Zs[4]  = { 0.f, 0.f, 0.f, 0.f };
  float smx[4] = { -3.4e38f, -3.4e38f, -3.4e38f, -3.4e38f };
  int   sag[4] = { 0, 0, 0, 0 };

  // cluster-col delta for pipeline step i (tile = (i>>1)*8 + w*2 + (i&1))
#define CDELT(i) ((((i) >> 1) * 128) + (((i) & 1) * 16))
#define BDELT(i) ((uint32_t)(CDELT(i)) * (uint32_t)ROWB)

#define LOADT(S, i)                                                           \
  {                                                                           \
    const uint32_t vo = rowoff + BDELT(i);                                    \
    bh0##S = *(const half8*)(cb + vo);                                        \
    bh1##S = *(const half8*)(cb + vo + 64);                                   \
    bl0##S = *(const half8*)(cb + vo + 128);                                  \
    bl1##S = *(const half8*)(cb + vo + 192);                                  \
    c2##S  = *(const float*)(cb + (vo - q * 16) + 256);                       \
  }

#define COMPT(S, i)                                                           \
  {                                                                           \
    f32x4 acc = { 0.f, 0.f, 0.f, 0.f };                                       \
    acc = __builtin_amdgcn_mfma_f32_16x16x32_f16(ah[0], bh0##S, acc, 0, 0, 0);\
    acc = __builtin_amdgcn_mfma_f32_16x16x32_f16(ah[1], bh1##S, acc, 0, 0, 0);\
    acc = __builtin_amdgcn_mfma_f32_16x16x32_f16(al[0], bh0##S, acc, 0, 0, 0);\
    acc = __builtin_amdgcn_mfma_f32_16x16x32_f16(al[1], bh1##S, acc, 0, 0, 0);\
    acc = __builtin_amdgcn_mfma_f32_16x16x32_f16(ah[0], bl0##S, acc, 0, 0, 0);\
    acc = __builtin_amdgcn_mfma_f32_16x16x32_f16(ah[1], bl1##S, acc, 0, 0, 0);\
    const uint32_t ncol = nbw + (uint32_t)CDELT(i);                           \
    const int colc = wcol + CDELT(i);                                         \
    _Pragma("unroll")                                                         \
    for (int r = 0; r < 4; ++r) {                                             \
      const float u2c2 = __fadd_rn(u2r[r], c2##S);                            \
      const float d2 = fmaxf(fmaf(-2.0f, acc[r], u2c2), 0.0f);                \
      const float qd = __builtin_amdgcn_sqrtf(__fadd_rn(d2, 1e-12f));         \
      const uint32_t bits = tf_bits32(kg0, kg1, ncol + (uint32_t)r * 4096u);  \
      const float u01 = __uint_as_float((bits >> 9) | 0x3f800000u) - 1.0f;    \
      const float gu = __fadd_rn(u01, 1e-10f);  /* >=1e-10 always: fmax dropped (exact) */ \
      const float g = -__logf(-__logf(gu));                                   \
      const float sc = __fsub_rn(g, qd);                                      \
      if (sc > smx[r]) { smx[r] = sc; sag[r] = colc; }                        \
      const float e = __expf(-qd);              /* exp(nd), no max-sub */     \
      ereg[(i) * 4 + r] = e;                                                  \
      Zs[r] = __fadd_rn(Zs[r], e);                                            \
    }                                                                         \
  }

  half8 bh0A, bh1A, bl0A, bl1A; float c2A;
  half8 bh0B, bh1B, bl0B, bl1B; float c2B;
  LOADT(A, 0)
  LOADT(B, 1)
  COMPT(A, 0)
  LOADT(A, 2)
  COMPT(B, 1)
  LOADT(B, 3)
  COMPT(A, 2)
  LOADT(A, 4)
  COMPT(B, 3)
  LOADT(B, 5)
  COMPT(A, 4)
  LOADT(A, 6)
  COMPT(B, 5)
  LOADT(B, 7)
  COMPT(A, 6)
  COMPT(B, 7)

  // reduce across the 16 lanes (same q) holding this row set
#pragma unroll
  for (int m = 1; m < 16; m <<= 1) {
#pragma unroll
    for (int r = 0; r < 4; ++r) {
      Zs[r] += __shfl_xor(Zs[r], m);
      const float os = __shfl_xor(smx[r], m);
      const int   oa = __shfl_xor(sag[r], m);
      if (os > smx[r] || (os == smx[r] && oa < sag[r])) { smx[r] = os; sag[r] = oa; }
    }
  }
  if (lr == 0) {
#pragma unroll
    for (int r = 0; r < 4; ++r) {
      zZ[w][q * 4 + r] = Zs[r];
      zS[w][q * 4 + r] = smx[r];
      zA[w][q * 4 + r] = sag[r];
    }
  }
  __syncthreads();

  // cross-wave combine (4 waves hold different cluster columns of same rows)
  float Zf[4]  = { 0.f, 0.f, 0.f, 0.f };
  float smf[4] = { -3.4e38f, -3.4e38f, -3.4e38f, -3.4e38f };
  int   saf[4] = { 0, 0, 0, 0 };
#pragma unroll
  for (int wv = 0; wv < 4; ++wv) {
    const float4 zz = *(const float4*)&zZ[wv][q * 4];
    const float4 ss = *(const float4*)&zS[wv][q * 4];
    const int4   aa = *(const int4*)&zA[wv][q * 4];
    const float zv[4] = { zz.x, zz.y, zz.z, zz.w };
    const float sv[4] = { ss.x, ss.y, ss.z, ss.w };
    const int   av[4] = { aa.x, aa.y, aa.z, aa.w };
#pragma unroll
    for (int r = 0; r < 4; ++r) {
      Zf[r] = __fadd_rn(Zf[r], zv[r]);
      if (sv[r] > smf[r] || (sv[r] == smf[r] && av[r] < saf[r])) {
        smf[r] = sv[r]; saf[r] = av[r];
      }
    }
  }

  float inv[4];
#pragma unroll
  for (int r = 0; r < 4; ++r) inv[r] = __builtin_amdgcn_rcpf(Zf[r]);

  float* obase = out_logits + ((size_t)(bbase + q * 4) * 8 + p) * 512 + wcol;
#pragma unroll
  for (int i = 0; i < 8; ++i)
#pragma unroll
    for (int r = 0; r < 4; ++r)
      obase[(size_t)r * 4096 + CDELT(i)] = ereg[i * 4 + r] * inv[r];

  if (w == 0 && lr == 0) {
#pragma unroll
    for (int r = 0; r < 4; ++r)
      sel[(bbase + q * 4 + r) * NPART + p] = saf[r];
  }
#undef CDELT
#undef BDELT
#undef LOADT
#undef COMPT
}

// ---------------------------------------------------------------------------
// Score kernel (unchanged, passed 3x): one 64-lane wave per b.
// ---------------------------------------------------------------------------
__global__ __launch_bounds__(256) void qvae_score_kernel(
    const float* __restrict__ centroids, const float* __restrict__ item_mu,
    const float* __restrict__ item_logvar, const int* __restrict__ item_id,
    const int* __restrict__ sel, float* __restrict__ out_score,
    uint32_t ke0, uint32_t ke1)
{
  const int lane = threadIdx.x & 63;
  const int b = blockIdx.x * 4 + (threadIdx.x >> 6);
  const int iid = item_id[b];
  const int pp = lane >> 3;
  const int sc = sel[b * NPART + pp];

  const float* cen = centroids + ((size_t)pp * NCLUS + sc) * DCL + (lane & 7) * 8;
  const float* mu = item_mu + (size_t)iid * DTOT + lane * 8;
  const float* lv = item_logvar + (size_t)iid * DTOT + lane * 8;

  const float4 m0 = *(const float4*)mu;
  const float4 m1 = *(const float4*)(mu + 4);
  const float4 l0 = *(const float4*)lv;
  const float4 l1 = *(const float4*)(lv + 4);
  const float4 q0 = *(const float4*)cen;
  const float4 q1 = *(const float4*)(cen + 4);
  const float mua[8] = { m0.x, m0.y, m0.z, m0.w, m1.x, m1.y, m1.z, m1.w };
  const float lva[8] = { l0.x, l0.y, l0.z, l0.w, l1.x, l1.y, l1.z, l1.w };
  const float cna[8] = { q0.x, q0.y, q0.z, q0.w, q1.x, q1.y, q1.z, q1.w };

  const float LO = __int_as_float(0xBF7FFFFFu);   // nextafter(-1,0)
  const float SQ2 = __int_as_float(0x3FB504F3u);  // float(sqrt(2))
  const uint32_t nb = (uint32_t)b * 512u + (uint32_t)lane * 8u;

  float acc = 0.f;
#pragma unroll
  for (int k = 0; k < 8; ++k) {
    const uint32_t bits = tf_bits32(ke0, ke1, nb + (uint32_t)k);
    const float u01 = __uint_as_float((bits >> 9) | 0x3f800000u) - 1.0f;
    const float uu = fmaxf(LO, __fadd_rn(__fmul_rn(u01, 2.0f), LO));
    const float eps = __fmul_rn(SQ2, erfinv_xla(uu));
    const float sd = __expf(__fmul_rn(0.5f, lva[k]));
    const float it = __fadd_rn(__fmul_rn(eps, sd), mua[k]);
    acc = fmaf(cna[k], it, acc);
  }
#pragma unroll
  for (int m = 1; m < 64; m <<= 1) acc += __shfl_xor(acc, m);
  if (lane == 0) out_score[b] = acc;
}

// ---------------------------------------------------------------------------
extern "C" void kernel_launch(void* const* d_in, const int* in_sizes, int n_in,
                              void* d_out, int out_size, void* d_ws, size_t ws_size,
                              hipStream_t stream)
{
  (void)in_sizes; (void)n_in; (void)out_size; (void)ws_size;

  const float* user_emb    = (const float*)d_in[0];
  const float* centroids   = (const float*)d_in[1];
  const float* item_mu     = (const float*)d_in[2];
  const float* item_logvar = (const float*)d_in[3];
  const int*   user_id     = (const int*)d_in[4];
  const int*   item_id     = (const int*)d_in[5];

  float* out_score  = (float*)d_out;            // [B]
  float* out_logits = (float*)d_out + B_TOT;    // [B,P,C]

  // ws layout: sel [B*P] int (1 MB) | cimg [P*C][272B] (1.09 MB, 16B-aligned)
  int*       sel  = (int*)d_ws;
  _Float16*  cimg = (_Float16*)((char*)d_ws + (size_t)B_TOT * NPART * 4);

  // host-side key derivation: key(42) = (0,42); foldlike split
  uint32_t kg0, kg1, ke0, ke1;
  tf2x32(0u, 42u, 0u, 0u, kg0, kg1);
  tf2x32(0u, 42u, 0u, 1u, ke0, ke1);

  qvae_prep_kernel<<<NPART * NCLUS / 256, 256, 0, stream>>>(centroids, cimg);

  dim3 g1(B_TOT / BTILE, NPART);
  qvae_main_kernel<<<g1, 256, 0, stream>>>(user_emb, cimg, user_id,
                                           out_logits, sel, kg0, kg1);
  qvae_score_kernel<<<B_TOT / 4, 256, 0, stream>>>(centroids, item_mu, item_logvar,
                                                   item_id, sel, out_score, ke0, ke1);
}